// Round 2
// baseline (698.812 us; speedup 1.0000x reference)
//
#include <hip/hip_runtime.h>

typedef unsigned short u16;
typedef unsigned int u32;
typedef short bf16x8 __attribute__((ext_vector_type(8)));
typedef float f32x4 __attribute__((ext_vector_type(4)));
typedef float f32x16 __attribute__((ext_vector_type(16)));

#define M_ROWS   66096      // 3888 frames * 17 joints
#define M_PAD    66176      // 517 * 128
#define C_DIM    512
#define NQKV     1536
#define NFRAME   3888

// ---------- helpers ----------

__device__ __forceinline__ u16 f2bf(float f) {
    u32 u = __float_as_uint(f);
    u32 r = (u + 0x7fffu + ((u >> 16) & 1u)) >> 16;   // RNE
    return (u16)r;
}
__device__ __forceinline__ float bf2f(u16 v) {
    return __uint_as_float(((u32)v) << 16);
}
__device__ __forceinline__ void async16(const void* g, void* l) {
    __builtin_amdgcn_global_load_lds(
        (const __attribute__((address_space(1))) unsigned int*)g,
        (__attribute__((address_space(3))) unsigned int*)l, 16, 0, 0);
}

// ---------- kernel 1: cast x -> bf16, K-tiled [kt][m][32], zero pad rows ----------

__global__ __launch_bounds__(256) void cast_x(const float* __restrict__ x, u16* __restrict__ xb) {
    u32 cid = blockIdx.x * 256u + threadIdx.x;      // one 8-elem chunk each
    u32 m  = cid >> 6;                              // 64 chunks per 512-row
    u32 c0 = (cid & 63u) * 8u;
    if (m >= M_PAD) return;
    u16 v[8];
    if (m < M_ROWS) {
        const float* p = x + (size_t)m * C_DIM + c0;
        float4 f1 = *(const float4*)p;
        float4 f2 = *(const float4*)(p + 4);
        v[0]=f2bf(f1.x); v[1]=f2bf(f1.y); v[2]=f2bf(f1.z); v[3]=f2bf(f1.w);
        v[4]=f2bf(f2.x); v[5]=f2bf(f2.y); v[6]=f2bf(f2.z); v[7]=f2bf(f2.w);
    } else {
        #pragma unroll
        for (int i = 0; i < 8; ++i) v[i] = 0;
    }
    u16* dst = xb + ((size_t)(c0 >> 5) * M_PAD + m) * 32 + (c0 & 31u);
    *(uint4*)dst = *(const uint4*)v;
}

// ---------- kernel 2: W (K x N) -> bf16 transposed+tiled [kt][n][32] ----------

__global__ __launch_bounds__(256) void cast_w(const float* __restrict__ W, u16* __restrict__ out, int N) {
    __shared__ float tile[32 * 65];
    const int n0 = blockIdx.x * 64;
    const int kt = blockIdx.y;
    const int t  = threadIdx.x;
    for (int i = t; i < 2048; i += 256) {
        int k = i >> 6, n = i & 63;
        tile[k * 65 + n] = W[(size_t)(kt * 32 + k) * N + n0 + n];
    }
    __syncthreads();
    {
        int n = t >> 2, kk0 = (t & 3) * 8;
        u16 v[8];
        #pragma unroll
        for (int j = 0; j < 8; ++j) v[j] = f2bf(tile[(kk0 + j) * 65 + n]);
        u16* dst = out + ((size_t)kt * N + n0 + n) * 32 + kk0;
        *(uint4*)dst = *(const uint4*)v;
    }
}

// ---------- kernel 3: QKV GEMM (66096x512 @ 512x1536) + bias, bf16 out ----------
// Double-buffered LDS, 2-phase prefetch: stage tile kt+1 while computing kt,
// ONE __syncthreads per tile.

__global__ __launch_bounds__(256) void gemm1(const u16* __restrict__ xb,   // [16][M_PAD][32]
                                             const u16* __restrict__ wt,   // [16][1536][32]
                                             const float* __restrict__ bqkv,
                                             u16* __restrict__ qkv) {      // [M_PAD][1536]
    __shared__ u16 As[2][128 * 32];
    __shared__ u16 Bs[2][128 * 32];
    __shared__ float biasS[128];

    const int n0 = blockIdx.x * 128;
    const int m0 = blockIdx.y * 128;
    const int t  = threadIdx.x;
    const int w  = t >> 6, l = t & 63;
    const int lr = l & 15, lq = l >> 4;
    const int wr = (w >> 1) * 64, wc = (w & 1) * 64;

    if (t < 128) biasS[t] = bqkv[n0 + t];

    f32x4 acc[4][4] = {};

    auto stage = [&](int kt, int bi) {
        const u16* ga = xb + ((size_t)kt * M_PAD + m0) * 32;
        const u16* gb = wt + ((size_t)kt * NQKV + n0) * 32;
        async16(ga + (size_t)t * 8,         &As[bi][t * 8]);
        async16(ga + (size_t)(t + 256) * 8, &As[bi][(t + 256) * 8]);
        async16(gb + (size_t)t * 8,         &Bs[bi][t * 8]);
        async16(gb + (size_t)(t + 256) * 8, &Bs[bi][(t + 256) * 8]);
    };

    stage(0, 0);
    __syncthreads();                      // drains vmcnt(0): tile 0 resident

    for (int kt = 0; kt < 16; ++kt) {
        const int cur = kt & 1;
        if (kt < 15) stage(kt + 1, cur ^ 1);   // prefetch overlaps compute below

        bf16x8 a[4], b[4];
        #pragma unroll
        for (int i = 0; i < 4; ++i) a[i] = *(const bf16x8*)&As[cur][(wr + i * 16 + lr) * 32 + lq * 8];
        #pragma unroll
        for (int i = 0; i < 4; ++i) b[i] = *(const bf16x8*)&Bs[cur][(wc + i * 16 + lr) * 32 + lq * 8];
        #pragma unroll
        for (int i = 0; i < 4; ++i)
            #pragma unroll
            for (int j = 0; j < 4; ++j)
                acc[i][j] = __builtin_amdgcn_mfma_f32_16x16x32_bf16(a[i], b[j], acc[i][j], 0, 0, 0);

        __syncthreads();                  // waits prefetch done + all reads of [cur] done
    }

    #pragma unroll
    for (int i = 0; i < 4; ++i) {
        #pragma unroll
        for (int j = 0; j < 4; ++j) {
            const int col  = n0 + wc + j * 16 + lr;
            const float bb = biasS[wc + j * 16 + lr];
            #pragma unroll
            for (int r = 0; r < 4; ++r) {
                const int row = m0 + wr + i * 16 + lq * 4 + r;
                if (row < M_ROWS)
                    qkv[(size_t)row * NQKV + col] = f2bf(acc[i][j][r] + bb);
            }
        }
    }
}

// ---------- kernel 4: attention — one wave per (frame,head), MFMA 32x32x16 ----------

__global__ __launch_bounds__(256) void attn_k(const u16* __restrict__ qkv, u16* __restrict__ xa) {
    __shared__ u16 Pb[4][32 * 40];   // per-wave P buffer, row stride 40 u16 (80B)

    const int wv  = threadIdx.x >> 6;
    const int l   = threadIdx.x & 63;
    const int l31 = l & 31;
    const int hi  = l >> 5;

    const int id = blockIdx.x * 4 + wv;   // (frame, head) id
    const int f  = id >> 3;
    const int h  = id & 7;

    const int mrow = (l31 < 17) ? l31 : 0;             // clamp pad rows
    const u16* base = qkv + (size_t)(f * 17) * NQKV;
    const u16* Qp = base + (size_t)mrow * NQKV + h * 64 + 8 * hi;
    const u16* Kp = Qp + 512;

    // ---- S = Q K^T (scaled later), 4 MFMAs over d=64 ----
    f32x16 Sacc = {};
    #pragma unroll
    for (int c = 0; c < 4; ++c) {
        bf16x8 aq = *(const bf16x8*)(Qp + 16 * c);
        bf16x8 bk = *(const bf16x8*)(Kp + 16 * c);
        Sacc = __builtin_amdgcn_mfma_f32_32x32x16_bf16(aq, bk, Sacc, 0, 0, 0);
    }

    // ---- mask pad cols, softmax per row ----
    float p[16];
    #pragma unroll
    for (int r = 0; r < 16; ++r)
        p[r] = (l31 < 17) ? Sacc[r] * 0.125f : -1e30f;

    #pragma unroll
    for (int r = 0; r < 16; ++r) {
        float mx = p[r];
        #pragma unroll
        for (int m = 1; m < 32; m <<= 1) mx = fmaxf(mx, __shfl_xor(mx, m));
        float e = __expf(p[r] - mx);
        float s = e;
        #pragma unroll
        for (int m = 1; m < 32; m <<= 1) s += __shfl_xor(s, m);
        p[r] = e * __builtin_amdgcn_rcpf(s);
    }

    // ---- sequential hierarchical triplets, in-register via readlane ----
    {
        constexpr int TJP[13] = {0,1,0,4,0,7,8,7,8,11,7,8,14};
        constexpr int TJ [13] = {1,2,4,5,7,8,9,8,11,12,8,14,15};
        constexpr int TJC[13] = {2,3,5,6,8,9,10,11,12,13,14,15,16};
        #pragma unroll
        for (int tr = 0; tr < 13; ++tr) {
            const int jp = TJP[tr], j = TJ[tr], jc = TJC[tr];
            const int rj = (j  & 3) | ((j  >> 3) << 2), hj = (j  >> 2) & 1;
            const int rc = (jc & 3) | ((jc >> 3) << 2), hc = (jc >> 2) & 1;
            const float half = 0.5f * __shfl(p[rj], jp + 32 * hj);
            if (l == jc + 32 * hj) p[rj] += half;   // S[j][jc] += half
            if (l == j  + 32 * hc) p[rc] += half;   // S[jc][j] += half
        }
    }

    // ---- C-layout -> A-layout via per-wave LDS round trip (bf16) ----
    u16* Pw = Pb[wv];
    #pragma unroll
    for (int r = 0; r < 16; ++r) {
        const int row = (r & 3) + 8 * (r >> 2) + 4 * hi;
        Pw[row * 40 + l31] = f2bf(p[r]);
    }
    asm volatile("s_waitcnt lgkmcnt(0)" ::: "memory");

    bf16x8 pa[2];
    #pragma unroll
    for (int c = 0; c < 2; ++c)
        pa[c] = *(const bf16x8*)&Pw[l31 * 40 + 16 * c + 8 * hi];

    // ---- O = P V ----
    const u16* Vbase = base + 1024 + h * 64;
    f32x16 O[2] = {};
    #pragma unroll
    for (int t = 0; t < 2; ++t) {
        #pragma unroll
        for (int c = 0; c < 2; ++c) {
            u16 vv[8];
            #pragma unroll
            for (int j = 0; j < 8; ++j) {
                const int k  = 16 * c + 8 * hi + j;
                const int kr = (k < 17) ? k : 0;      // P cols >=17 are 0
                vv[j] = Vbase[(size_t)kr * NQKV + t * 32 + l31];
            }
            O[t] = __builtin_amdgcn_mfma_f32_32x32x16_bf16(pa[c], *(const bf16x8*)vv, O[t], 0, 0, 0);
        }
    }

    // ---- store xa in gemm2's K-tiled layout [kt][m][32] ----
    #pragma unroll
    for (int t = 0; t < 2; ++t) {
        const int kt = h * 2 + t;
        #pragma unroll
        for (int r = 0; r < 16; ++r) {
            const int row = (r & 3) + 8 * (r >> 2) + 4 * hi;
            if (row < 17)
                xa[((size_t)kt * M_PAD + (f * 17 + row)) * 32 + l31] = f2bf(O[t][r]);
        }
    }
}

// ---------- kernel 5: proj GEMM + bias + residual + LayerNorm, fused ----------
// BM=128, BN=512 (full row slab -> LN fusable). 512 threads = 8 waves,
// wave wn owns all 128 rows x 64 cols (acc[8][4]).
// LDS-free K-loop with EXPLICIT 2-deep register double-buffer: loads for
// tile k+1 issue before the 32-MFMA cluster of tile k, so ~12 loads/wave
// stay in flight under compute (x 2 waves/SIMD).

#define G2_LOAD(kt, Af, Bf)                                                          \
    {                                                                                \
        const u16* ga = xa + ((size_t)(kt) * M_PAD + m0 + lr) * 32 + lq * 8;         \
        const u16* gb = wt + ((size_t)(kt) * C_DIM + wn * 64 + lr) * 32 + lq * 8;    \
        _Pragma("unroll") for (int i = 0; i < 8; ++i)                                \
            Af[i] = *(const bf16x8*)(ga + (size_t)i * 512);                          \
        _Pragma("unroll") for (int j = 0; j < 4; ++j)                                \
            Bf[j] = *(const bf16x8*)(gb + (size_t)j * 512);                          \
    }

#define G2_MFMA(Af, Bf)                                                              \
    _Pragma("unroll") for (int i = 0; i < 8; ++i)                                    \
        _Pragma("unroll") for (int j = 0; j < 4; ++j)                                \
            acc[i][j] = __builtin_amdgcn_mfma_f32_16x16x32_bf16(Af[i], Bf[j], acc[i][j], 0, 0, 0);

__global__ __launch_bounds__(512, 2) void gemm2_ln(const u16* __restrict__ xa,   // [16][M_PAD][32]
                                                   const u16* __restrict__ wt,   // [16][512][32]
                                                   const float* __restrict__ bproj,
                                                   const float* __restrict__ x,
                                                   float* __restrict__ out) {
    __shared__ float partS[128][9];      // [row][wave] sums (+1 pad col reused)
    __shared__ float partQ[128][9];      // [row][wave] sumsq

    const int m0 = blockIdx.x * 128;
    const int t  = threadIdx.x;
    const int wn = t >> 6, l = t & 63;
    const int lr = l & 15, lq = l >> 4;

    f32x4 acc[8][4] = {};
    bf16x8 A0[8], B0[4], A1[8], B1[4];

    G2_LOAD(0, A0, B0);
    #pragma unroll 1
    for (int kt = 0; kt < 14; kt += 2) {
        G2_LOAD(kt + 1, A1, B1);
        G2_MFMA(A0, B0);
        G2_LOAD(kt + 2, A0, B0);
        G2_MFMA(A1, B1);
    }
    G2_LOAD(15, A1, B1);
    G2_MFMA(A0, B0);
    G2_MFMA(A1, B1);

    // ---- epilogue: +bias +residual, per-row (sum,sumsq) ----
    float bias_[4];
    #pragma unroll
    for (int j = 0; j < 4; ++j) bias_[j] = bproj[wn * 64 + j * 16 + lr];

    #pragma unroll
    for (int i = 0; i < 8; ++i) {
        #pragma unroll
        for (int rr = 0; rr < 4; ++rr) {
            const int rl   = i * 16 + lq * 4 + rr;
            const int rowg = m0 + rl;
            const bool valid = rowg < M_ROWS;
            const float* xr = x + (size_t)rowg * C_DIM + wn * 64 + lr;
            float s = 0.f, q = 0.f;
            #pragma unroll
            for (int j = 0; j < 4; ++j) {
                float v = acc[i][j][rr] + bias_[j];
                if (valid) v += xr[j * 16];
                acc[i][j][rr] = v;
                s += v;
                q += v * v;
            }
            #pragma unroll
            for (int m = 1; m < 16; m <<= 1) {
                s += __shfl_xor(s, m);
                q += __shfl_xor(q, m);
            }
            if (lr == 0) {
                partS[rl][wn] = s;
                partQ[rl][wn] = q;
            }
        }
    }
    __syncthreads();

    // cooperative per-row reduce over 8 waves -> mean, rstd
    if (t < 128) {
        float ss = 0.f, qq = 0.f;
        #pragma unroll
        for (int w2 = 0; w2 < 8; ++w2) { ss += partS[t][w2]; qq += partQ[t][w2]; }
        const float mean = ss * (1.f / 512.f);
        const float var  = qq * (1.f / 512.f) - mean * mean;
        partS[t][8] = mean;
        partQ[t][8] = rsqrtf(var + 1e-5f);
    }
    __syncthreads();

    #pragma unroll
    for (int i = 0; i < 8; ++i) {
        #pragma unroll
        for (int rr = 0; rr < 4; ++rr) {
            const int rl   = i * 16 + lq * 4 + rr;
            const int rowg = m0 + rl;
            if (rowg < M_ROWS) {
                const float mean = partS[rl][8];
                const float rstd = partQ[rl][8];
                float* orow = out + (size_t)rowg * C_DIM + wn * 64 + lr;
                #pragma unroll
                for (int j = 0; j < 4; ++j)
                    orow[j * 16] = (acc[i][j][rr] - mean) * rstd;
            }
        }
    }
}

// ---------- launch ----------

extern "C" void kernel_launch(void* const* d_in, const int* in_sizes, int n_in,
                              void* d_out, int out_size, void* d_ws, size_t ws_size,
                              hipStream_t stream) {
    const float* x     = (const float*)d_in[0];
    const float* Wqkv  = (const float*)d_in[1];
    const float* bqkv  = (const float*)d_in[2];
    const float* Wproj = (const float*)d_in[3];
    const float* bproj = (const float*)d_in[4];
    float* out = (float*)d_out;

    u16* xb  = (u16*)d_ws;                              // M_PAD*512
    u16* wqt = xb  + (size_t)M_PAD * C_DIM;             // 1536*512
    u16* wpt = wqt + (size_t)NQKV * C_DIM;              // 512*512
    u16* qkv = wpt + (size_t)C_DIM * C_DIM;             // M_PAD*1536 (bf16)
    u16* xa  = qkv + (size_t)M_PAD * NQKV;              // M_PAD*512

    cast_x<<<(M_PAD * 64) / 256, 256, 0, stream>>>(x, xb);
    cast_w<<<dim3(NQKV / 64, 16), 256, 0, stream>>>(Wqkv, wqt, NQKV);
    cast_w<<<dim3(C_DIM / 64, 16), 256, 0, stream>>>(Wproj, wpt, C_DIM);
    gemm1<<<dim3(NQKV / 128, M_PAD / 128), 256, 0, stream>>>(xb, wqt, bqkv, qkv);
    attn_k<<<(NFRAME * 8) / 4, 256, 0, stream>>>(qkv, xa);
    gemm2_ln<<<(M_PAD / 128), 512, 0, stream>>>(xa, wpt, bproj, x, out);
}

// Round 3
// 631.235 us; speedup vs baseline: 1.1071x; 1.1071x over previous
//
#include <hip/hip_runtime.h>

typedef unsigned short u16;
typedef unsigned int u32;
typedef short bf16x8 __attribute__((ext_vector_type(8)));
typedef float f32x4 __attribute__((ext_vector_type(4)));
typedef float f32x16 __attribute__((ext_vector_type(16)));

#define M_ROWS   66096      // 3888 frames * 17 joints
#define M_PAD    66176      // 517 * 128 (= 1034 * 64)
#define C_DIM    512
#define NQKV     1536
#define NFRAME   3888

// ---------- helpers ----------

__device__ __forceinline__ u16 f2bf(float f) {
    u32 u = __float_as_uint(f);
    u32 r = (u + 0x7fffu + ((u >> 16) & 1u)) >> 16;   // RNE
    return (u16)r;
}
__device__ __forceinline__ float bf2f(u16 v) {
    return __uint_as_float(((u32)v) << 16);
}
__device__ __forceinline__ void async16(const void* g, void* l) {
    __builtin_amdgcn_global_load_lds(
        (const __attribute__((address_space(1))) unsigned int*)g,
        (__attribute__((address_space(3))) unsigned int*)l, 16, 0, 0);
}

// ---------- kernel 1: cast x -> bf16, K-tiled [kt][m][32], zero pad rows ----------

__global__ __launch_bounds__(256) void cast_x(const float* __restrict__ x, u16* __restrict__ xb) {
    u32 cid = blockIdx.x * 256u + threadIdx.x;      // one 8-elem chunk each
    u32 m  = cid >> 6;                              // 64 chunks per 512-row
    u32 c0 = (cid & 63u) * 8u;
    if (m >= M_PAD) return;
    u16 v[8];
    if (m < M_ROWS) {
        const float* p = x + (size_t)m * C_DIM + c0;
        float4 f1 = *(const float4*)p;
        float4 f2 = *(const float4*)(p + 4);
        v[0]=f2bf(f1.x); v[1]=f2bf(f1.y); v[2]=f2bf(f1.z); v[3]=f2bf(f1.w);
        v[4]=f2bf(f2.x); v[5]=f2bf(f2.y); v[6]=f2bf(f2.z); v[7]=f2bf(f2.w);
    } else {
        #pragma unroll
        for (int i = 0; i < 8; ++i) v[i] = 0;
    }
    u16* dst = xb + ((size_t)(c0 >> 5) * M_PAD + m) * 32 + (c0 & 31u);
    *(uint4*)dst = *(const uint4*)v;
}

// ---------- kernel 2: W (K x N) -> bf16 transposed+tiled [kt][n][32] ----------

__global__ __launch_bounds__(256) void cast_w(const float* __restrict__ W, u16* __restrict__ out, int N) {
    __shared__ float tile[32 * 65];
    const int n0 = blockIdx.x * 64;
    const int kt = blockIdx.y;
    const int t  = threadIdx.x;
    for (int i = t; i < 2048; i += 256) {
        int k = i >> 6, n = i & 63;
        tile[k * 65 + n] = W[(size_t)(kt * 32 + k) * N + n0 + n];
    }
    __syncthreads();
    {
        int n = t >> 2, kk0 = (t & 3) * 8;
        u16 v[8];
        #pragma unroll
        for (int j = 0; j < 8; ++j) v[j] = f2bf(tile[(kk0 + j) * 65 + n]);
        u16* dst = out + ((size_t)kt * N + n0 + n) * 32 + kk0;
        *(uint4*)dst = *(const uint4*)v;
    }
}

// ---------- kernel 3: QKV GEMM (66096x512 @ 512x1536) + bias, bf16 out ----------
// Double-buffered LDS, stage tile kt+1 while computing kt, ONE __syncthreads/tile.

__global__ __launch_bounds__(256) void gemm1(const u16* __restrict__ xb,   // [16][M_PAD][32]
                                             const u16* __restrict__ wt,   // [16][1536][32]
                                             const float* __restrict__ bqkv,
                                             u16* __restrict__ qkv) {      // [M_PAD][1536]
    __shared__ u16 As[2][128 * 32];
    __shared__ u16 Bs[2][128 * 32];
    __shared__ float biasS[128];

    const int n0 = blockIdx.x * 128;
    const int m0 = blockIdx.y * 128;
    const int t  = threadIdx.x;
    const int w  = t >> 6, l = t & 63;
    const int lr = l & 15, lq = l >> 4;
    const int wr = (w >> 1) * 64, wc = (w & 1) * 64;

    if (t < 128) biasS[t] = bqkv[n0 + t];

    f32x4 acc[4][4] = {};

    auto stage = [&](int kt, int bi) {
        const u16* ga = xb + ((size_t)kt * M_PAD + m0) * 32;
        const u16* gb = wt + ((size_t)kt * NQKV + n0) * 32;
        async16(ga + (size_t)t * 8,         &As[bi][t * 8]);
        async16(ga + (size_t)(t + 256) * 8, &As[bi][(t + 256) * 8]);
        async16(gb + (size_t)t * 8,         &Bs[bi][t * 8]);
        async16(gb + (size_t)(t + 256) * 8, &Bs[bi][(t + 256) * 8]);
    };

    stage(0, 0);
    __syncthreads();                      // drains vmcnt(0): tile 0 resident

    for (int kt = 0; kt < 16; ++kt) {
        const int cur = kt & 1;
        if (kt < 15) stage(kt + 1, cur ^ 1);   // prefetch overlaps compute below

        bf16x8 a[4], b[4];
        #pragma unroll
        for (int i = 0; i < 4; ++i) a[i] = *(const bf16x8*)&As[cur][(wr + i * 16 + lr) * 32 + lq * 8];
        #pragma unroll
        for (int i = 0; i < 4; ++i) b[i] = *(const bf16x8*)&Bs[cur][(wc + i * 16 + lr) * 32 + lq * 8];
        #pragma unroll
        for (int i = 0; i < 4; ++i)
            #pragma unroll
            for (int j = 0; j < 4; ++j)
                acc[i][j] = __builtin_amdgcn_mfma_f32_16x16x32_bf16(a[i], b[j], acc[i][j], 0, 0, 0);

        __syncthreads();                  // waits prefetch done + all reads of [cur] done
    }

    #pragma unroll
    for (int i = 0; i < 4; ++i) {
        #pragma unroll
        for (int j = 0; j < 4; ++j) {
            const int col  = n0 + wc + j * 16 + lr;
            const float bb = biasS[wc + j * 16 + lr];
            #pragma unroll
            for (int r = 0; r < 4; ++r) {
                const int row = m0 + wr + i * 16 + lq * 4 + r;
                if (row < M_ROWS)
                    qkv[(size_t)row * NQKV + col] = f2bf(acc[i][j][r] + bb);
            }
        }
    }
}

// ---------- kernel 4: attention — one wave per (frame,head), MFMA 32x32x16 ----------

__global__ __launch_bounds__(256) void attn_k(const u16* __restrict__ qkv, u16* __restrict__ xa) {
    __shared__ u16 Pb[4][32 * 40];   // per-wave P buffer, row stride 40 u16 (80B)

    const int wv  = threadIdx.x >> 6;
    const int l   = threadIdx.x & 63;
    const int l31 = l & 31;
    const int hi  = l >> 5;

    const int id = blockIdx.x * 4 + wv;   // (frame, head) id
    const int f  = id >> 3;
    const int h  = id & 7;

    const int mrow = (l31 < 17) ? l31 : 0;             // clamp pad rows
    const u16* base = qkv + (size_t)(f * 17) * NQKV;
    const u16* Qp = base + (size_t)mrow * NQKV + h * 64 + 8 * hi;
    const u16* Kp = Qp + 512;

    // ---- S = Q K^T (scaled later), 4 MFMAs over d=64 ----
    f32x16 Sacc = {};
    #pragma unroll
    for (int c = 0; c < 4; ++c) {
        bf16x8 aq = *(const bf16x8*)(Qp + 16 * c);
        bf16x8 bk = *(const bf16x8*)(Kp + 16 * c);
        Sacc = __builtin_amdgcn_mfma_f32_32x32x16_bf16(aq, bk, Sacc, 0, 0, 0);
    }

    // ---- mask pad cols, softmax per row ----
    float p[16];
    #pragma unroll
    for (int r = 0; r < 16; ++r)
        p[r] = (l31 < 17) ? Sacc[r] * 0.125f : -1e30f;

    #pragma unroll
    for (int r = 0; r < 16; ++r) {
        float mx = p[r];
        #pragma unroll
        for (int m = 1; m < 32; m <<= 1) mx = fmaxf(mx, __shfl_xor(mx, m));
        float e = __expf(p[r] - mx);
        float s = e;
        #pragma unroll
        for (int m = 1; m < 32; m <<= 1) s += __shfl_xor(s, m);
        p[r] = e * __builtin_amdgcn_rcpf(s);
    }

    // ---- sequential hierarchical triplets, in-register via readlane ----
    {
        constexpr int TJP[13] = {0,1,0,4,0,7,8,7,8,11,7,8,14};
        constexpr int TJ [13] = {1,2,4,5,7,8,9,8,11,12,8,14,15};
        constexpr int TJC[13] = {2,3,5,6,8,9,10,11,12,13,14,15,16};
        #pragma unroll
        for (int tr = 0; tr < 13; ++tr) {
            const int jp = TJP[tr], j = TJ[tr], jc = TJC[tr];
            const int rj = (j  & 3) | ((j  >> 3) << 2), hj = (j  >> 2) & 1;
            const int rc = (jc & 3) | ((jc >> 3) << 2), hc = (jc >> 2) & 1;
            const float half = 0.5f * __shfl(p[rj], jp + 32 * hj);
            if (l == jc + 32 * hj) p[rj] += half;   // S[j][jc] += half
            if (l == j  + 32 * hc) p[rc] += half;   // S[jc][j] += half
        }
    }

    // ---- C-layout -> A-layout via per-wave LDS round trip (bf16) ----
    u16* Pw = Pb[wv];
    #pragma unroll
    for (int r = 0; r < 16; ++r) {
        const int row = (r & 3) + 8 * (r >> 2) + 4 * hi;
        Pw[row * 40 + l31] = f2bf(p[r]);
    }
    asm volatile("s_waitcnt lgkmcnt(0)" ::: "memory");

    bf16x8 pa[2];
    #pragma unroll
    for (int c = 0; c < 2; ++c)
        pa[c] = *(const bf16x8*)&Pw[l31 * 40 + 16 * c + 8 * hi];

    // ---- O = P V ----
    const u16* Vbase = base + 1024 + h * 64;
    f32x16 O[2] = {};
    #pragma unroll
    for (int t = 0; t < 2; ++t) {
        #pragma unroll
        for (int c = 0; c < 2; ++c) {
            u16 vv[8];
            #pragma unroll
            for (int j = 0; j < 8; ++j) {
                const int k  = 16 * c + 8 * hi + j;
                const int kr = (k < 17) ? k : 0;      // P cols >=17 are 0
                vv[j] = Vbase[(size_t)kr * NQKV + t * 32 + l31];
            }
            O[t] = __builtin_amdgcn_mfma_f32_32x32x16_bf16(pa[c], *(const bf16x8*)vv, O[t], 0, 0, 0);
        }
    }

    // ---- store xa in gemm2's K-tiled layout [kt][m][32] ----
    #pragma unroll
    for (int t = 0; t < 2; ++t) {
        const int kt = h * 2 + t;
        #pragma unroll
        for (int r = 0; r < 16; ++r) {
            const int row = (r & 3) + 8 * (r >> 2) + 4 * hi;
            if (row < 17)
                xa[((size_t)kt * M_PAD + (f * 17 + row)) * 32 + l31] = f2bf(O[t][r]);
        }
    }
}

// ---------- kernel 5: proj GEMM + bias + residual + LayerNorm, fused ----------
// BM=64, BN=512 (full row slab -> LN fusable). 512 threads = 8 waves;
// wave wn owns all 64 rows x 64 cols (acc[4][4], 64 AGPRs).
// global_load_lds staged, double-buffered, ONE __syncthreads per K-tile
// (hardware-queued DMA: compiler cannot serialize it, unlike reg loads).
// LDS 77 KB -> 2 blocks/CU (4 waves/SIMD); cross-block overlap covers drains.

__global__ __launch_bounds__(512, 4) void gemm2_ln(const u16* __restrict__ xa,   // [16][M_PAD][32]
                                                   const u16* __restrict__ wt,   // [16][512][32]
                                                   const float* __restrict__ bproj,
                                                   const float* __restrict__ x,
                                                   float* __restrict__ out) {
    __shared__ u16 As[2][64 * 32];       // 4 KB each
    __shared__ u16 Bs[2][512 * 32];      // 32 KB each
    __shared__ float partS[64][9];       // [row][wave] sums, col 8 = mean
    __shared__ float partQ[64][9];       // [row][wave] sumsq, col 8 = rstd

    const int m0 = blockIdx.x * 64;
    const int t  = threadIdx.x;
    const int wn = t >> 6, l = t & 63;
    const int lr = l & 15, lq = l >> 4;

    f32x4 acc[4][4] = {};

    auto stage = [&](int kt, int bi) {
        const u16* ga = xa + ((size_t)kt * M_PAD + m0) * 32;
        const u16* gb = wt + ((size_t)kt * C_DIM) * 32;
        if (t < 256) async16(ga + (size_t)t * 8, &As[bi][t * 8]);
        #pragma unroll
        for (int i = 0; i < 4; ++i)
            async16(gb + (size_t)(t + 512 * i) * 8, &Bs[bi][(t + 512 * i) * 8]);
    };

    stage(0, 0);
    __syncthreads();                      // tile 0 resident

    for (int kt = 0; kt < 16; ++kt) {
        const int cur = kt & 1;
        if (kt < 15) stage(kt + 1, cur ^ 1);   // prefetch overlaps compute

        bf16x8 a[4], b[4];
        #pragma unroll
        for (int i = 0; i < 4; ++i) a[i] = *(const bf16x8*)&As[cur][(i * 16 + lr) * 32 + lq * 8];
        #pragma unroll
        for (int j = 0; j < 4; ++j) b[j] = *(const bf16x8*)&Bs[cur][(wn * 64 + j * 16 + lr) * 32 + lq * 8];
        #pragma unroll
        for (int i = 0; i < 4; ++i)
            #pragma unroll
            for (int j = 0; j < 4; ++j)
                acc[i][j] = __builtin_amdgcn_mfma_f32_16x16x32_bf16(a[i], b[j], acc[i][j], 0, 0, 0);

        __syncthreads();
    }

    // ---- epilogue: +bias +residual, per-row (sum,sumsq) ----
    float bias_[4];
    #pragma unroll
    for (int j = 0; j < 4; ++j) bias_[j] = bproj[wn * 64 + j * 16 + lr];

    #pragma unroll
    for (int i = 0; i < 4; ++i) {
        #pragma unroll
        for (int rr = 0; rr < 4; ++rr) {
            const int rl   = i * 16 + lq * 4 + rr;
            const int rowg = m0 + rl;
            const bool valid = rowg < M_ROWS;
            const float* xr = x + (size_t)rowg * C_DIM + wn * 64 + lr;
            float s = 0.f, q = 0.f;
            #pragma unroll
            for (int j = 0; j < 4; ++j) {
                float v = acc[i][j][rr] + bias_[j];
                if (valid) v += xr[j * 16];
                acc[i][j][rr] = v;
                s += v;
                q += v * v;
            }
            #pragma unroll
            for (int m = 1; m < 16; m <<= 1) {     // reduce over the 16 lr lanes
                s += __shfl_xor(s, m);
                q += __shfl_xor(q, m);
            }
            if (lr == 0) {
                partS[rl][wn] = s;
                partQ[rl][wn] = q;
            }
        }
    }
    __syncthreads();

    // cooperative per-row reduce over 8 waves -> mean, rstd
    if (t < 64) {
        float ss = 0.f, qq = 0.f;
        #pragma unroll
        for (int w2 = 0; w2 < 8; ++w2) { ss += partS[t][w2]; qq += partQ[t][w2]; }
        const float mean = ss * (1.f / 512.f);
        const float var  = qq * (1.f / 512.f) - mean * mean;
        partS[t][8] = mean;
        partQ[t][8] = rsqrtf(var + 1e-5f);
    }
    __syncthreads();

    #pragma unroll
    for (int i = 0; i < 4; ++i) {
        #pragma unroll
        for (int rr = 0; rr < 4; ++rr) {
            const int rl   = i * 16 + lq * 4 + rr;
            const int rowg = m0 + rl;
            if (rowg < M_ROWS) {
                const float mean = partS[rl][8];
                const float rstd = partQ[rl][8];
                float* orow = out + (size_t)rowg * C_DIM + wn * 64 + lr;
                #pragma unroll
                for (int j = 0; j < 4; ++j)
                    orow[j * 16] = (acc[i][j][rr] - mean) * rstd;
            }
        }
    }
}

// ---------- launch ----------

extern "C" void kernel_launch(void* const* d_in, const int* in_sizes, int n_in,
                              void* d_out, int out_size, void* d_ws, size_t ws_size,
                              hipStream_t stream) {
    const float* x     = (const float*)d_in[0];
    const float* Wqkv  = (const float*)d_in[1];
    const float* bqkv  = (const float*)d_in[2];
    const float* Wproj = (const float*)d_in[3];
    const float* bproj = (const float*)d_in[4];
    float* out = (float*)d_out;

    u16* xb  = (u16*)d_ws;                              // M_PAD*512
    u16* wqt = xb  + (size_t)M_PAD * C_DIM;             // 1536*512
    u16* wpt = wqt + (size_t)NQKV * C_DIM;              // 512*512
    u16* qkv = wpt + (size_t)C_DIM * C_DIM;             // M_PAD*1536 (bf16)
    u16* xa  = qkv + (size_t)M_PAD * NQKV;              // M_PAD*512

    cast_x<<<(M_PAD * 64) / 256, 256, 0, stream>>>(x, xb);
    cast_w<<<dim3(NQKV / 64, 16), 256, 0, stream>>>(Wqkv, wqt, NQKV);
    cast_w<<<dim3(C_DIM / 64, 16), 256, 0, stream>>>(Wproj, wpt, C_DIM);
    gemm1<<<dim3(NQKV / 128, M_PAD / 128), 256, 0, stream>>>(xb, wqt, bqkv, qkv);
    attn_k<<<(NFRAME * 8) / 4, 256, 0, stream>>>(qkv, xa);
    gemm2_ln<<<(M_PAD / 64), 512, 0, stream>>>(xa, wpt, bproj, x, out);
}